// Round 6
// baseline (63934.680 us; speedup 1.0000x reference)
//
#include <hip/hip_runtime.h>
#include <hip/hip_bf16.h>
#include <stdint.h>

#define B  64
#define TD 512
#define TE 1024
#define EE 512
#define UU 256

// ---------- numeric helpers ----------
__device__ __forceinline__ float fexp2(float x){ return __builtin_amdgcn_exp2f(x); }
__device__ __forceinline__ float frcp_(float x){ return __builtin_amdgcn_rcpf(x); }
__device__ __forceinline__ float tanh_fast(float x){
  float e = fexp2(x * 2.885390082f);
  return 1.f - 2.f * frcp_(e + 1.f);
}
__device__ __forceinline__ float sigmoid_fast(float x){
  return frcp_(1.f + fexp2(-1.442695041f * x));
}
__device__ __forceinline__ unsigned short f2bf(float f){
  unsigned int u = __float_as_uint(f);
  u = (u + 0x7fffu + ((u >> 16) & 1u)) >> 16;   // RNE
  return (unsigned short)u;
}
__device__ __forceinline__ float bflo(unsigned int w){ return __uint_as_float(w << 16); }
__device__ __forceinline__ float bfhi(unsigned int w){ return __uint_as_float(w & 0xffff0000u); }

// Cross-XCD comm WITHOUT cache flushes: relaxed system-scope ops lower to
// global_load/store/atomic with sc0 sc1 (bypass L1/L2, coherent at L3) and
// never emit buffer_inv/buffer_wbl2 -> L2 stays hot for speech/KRP.
__device__ __forceinline__ void gstore(float* p, float v){
  __hip_atomic_store(p, v, __ATOMIC_RELAXED, __HIP_MEMORY_SCOPE_SYSTEM);
}
__device__ __forceinline__ float gload(const float* p){
  return __hip_atomic_load(p, __ATOMIC_RELAXED, __HIP_MEMORY_SCOPE_SYSTEM);
}
__device__ __forceinline__ void gstore_u(unsigned int* p, unsigned int v){
  __hip_atomic_store(p, v, __ATOMIC_RELAXED, __HIP_MEMORY_SCOPE_SYSTEM);
}
__device__ __forceinline__ unsigned int gload_u(const unsigned int* p){
  return __hip_atomic_load(p, __ATOMIC_RELAXED, __HIP_MEMORY_SCOPE_SYSTEM);
}
__device__ __forceinline__ void drain_stores(){
  __atomic_signal_fence(__ATOMIC_SEQ_CST);
  __builtin_amdgcn_s_waitcnt(0);
  __atomic_signal_fence(__ATOMIC_SEQ_CST);
}

// Gate partial GEMV (512-thread WG, 128 output columns) over k-range
// [k0, k0+32*NITER). c = j-chunk (8 of 128 cols), kg = k-group. Lanes
// {l, l+16, l+32, l+48} share c -> 2-step shfl reduce, lane<16 atomics.
template<int NITER>
__device__ __forceinline__ void gate_accum8(const unsigned short* __restrict__ KRP,
    const float* catp, float* zb, int q8, int k0, int tid, int lane){
  const int c = tid & 15, kg = tid >> 4;     // kg in [0,32)
  const uint4* kp = (const uint4*)KRP + ((size_t)q8*1024 + k0 + kg*NITER)*16 + c;
  float a0=0.f,a1=0.f,a2=0.f,a3=0.f,a4=0.f,a5=0.f,a6=0.f,a7=0.f;
  #pragma unroll 4
  for (int i = 0; i < NITER; ++i){
    uint4 w = kp[(size_t)i*16];
    float ck = catp[k0 + kg*NITER + i];
    a0 += ck*bflo(w.x); a1 += ck*bfhi(w.x);
    a2 += ck*bflo(w.y); a3 += ck*bfhi(w.y);
    a4 += ck*bflo(w.z); a5 += ck*bfhi(w.z);
    a6 += ck*bflo(w.w); a7 += ck*bfhi(w.w);
  }
  a0 += __shfl_xor(a0, 16); a1 += __shfl_xor(a1, 16);
  a2 += __shfl_xor(a2, 16); a3 += __shfl_xor(a3, 16);
  a4 += __shfl_xor(a4, 16); a5 += __shfl_xor(a5, 16);
  a6 += __shfl_xor(a6, 16); a7 += __shfl_xor(a7, 16);
  a0 += __shfl_xor(a0, 32); a1 += __shfl_xor(a1, 32);
  a2 += __shfl_xor(a2, 32); a3 += __shfl_xor(a3, 32);
  a4 += __shfl_xor(a4, 32); a5 += __shfl_xor(a5, 32);
  a6 += __shfl_xor(a6, 32); a7 += __shfl_xor(a7, 32);
  if (lane < 16){
    atomicAdd(&zb[c*8+0], a0); atomicAdd(&zb[c*8+1], a1);
    atomicAdd(&zb[c*8+2], a2); atomicAdd(&zb[c*8+3], a3);
    atomicAdd(&zb[c*8+4], a4); atomicAdd(&zb[c*8+5], a5);
    atomicAdd(&zb[c*8+6], a6); atomicAdd(&zb[c*8+7], a7);
  }
}

// ---------- pack kernels ----------
__global__ void pack_bf16v(const float* __restrict__ in, unsigned short* __restrict__ out, int n4){
  int i = blockIdx.x * blockDim.x + threadIdx.x;
  int stride = gridDim.x * blockDim.x;
  for (; i < n4; i += stride){
    float4 v = ((const float4*)in)[i];
    ushort4 o;
    o.x = f2bf(v.x); o.y = f2bf(v.y); o.z = f2bf(v.z); o.w = f2bf(v.w);
    ((ushort4*)out)[i] = o;
  }
}

// KRP[q8][k][jj]: per-WG-contiguous gate weights for 8 WGs/batch. jj in
// [0,128) maps to logical column J = (jj>>5)*256 + q8*32 + (jj&31);
// rows 0..767 = K, 768..1023 = R. Total 8*1024*128 = 1,048,576 elements
// -> grid MUST be 4096 x 256 exactly.
__global__ void pack_KRP(const float* __restrict__ K, const float* __restrict__ R,
                         unsigned short* __restrict__ KRP){
  int idx = blockIdx.x * 256 + threadIdx.x;    // 4096 blocks -> 1M exactly
  int q8 = idx >> 17;
  int k  = (idx >> 7) & 1023;
  int jj = idx & 127;
  int J  = (jj >> 5)*256 + q8*32 + (jj & 31);
  float v = (k < 768) ? K[(size_t)k*1024 + J] : R[(size_t)(k - 768)*1024 + J];
  KRP[idx] = f2bf(v);
}

// ---------- secrets = trans @ emb_W + emb_b : [32768,64]@[64,256] ----------
__global__ __launch_bounds__(256) void emb_gemm(const float* __restrict__ trans,
    const float* __restrict__ W, const float* __restrict__ bias, float* __restrict__ out){
  __shared__ __align__(16) float aT[64*20];
  const int row0 = blockIdx.x * 16;
  const int tid = threadIdx.x;
  {
    int r = tid >> 6, k = tid & 63;
    for (int rr = r; rr < 16; rr += 4)
      aT[k*20 + rr] = trans[(size_t)(row0 + rr)*64 + k];
  }
  __syncthreads();
  const int j = tid;
  float bj = bias[j];
  float acc[16];
  #pragma unroll
  for (int r = 0; r < 16; ++r) acc[r] = bj;
  for (int k = 0; k < 64; ++k){
    float w = W[(size_t)k*UU + j];
    const float4* a4 = (const float4*)(aT + k*20);
    float4 q0 = a4[0], q1 = a4[1], q2 = a4[2], q3 = a4[3];
    acc[0]+=q0.x*w;  acc[1]+=q0.y*w;  acc[2]+=q0.z*w;  acc[3]+=q0.w*w;
    acc[4]+=q1.x*w;  acc[5]+=q1.y*w;  acc[6]+=q1.z*w;  acc[7]+=q1.w*w;
    acc[8]+=q2.x*w;  acc[9]+=q2.y*w;  acc[10]+=q2.z*w; acc[11]+=q2.w*w;
    acc[12]+=q3.x*w; acc[13]+=q3.y*w; acc[14]+=q3.z*w; acc[15]+=q3.w*w;
  }
  #pragma unroll
  for (int r = 0; r < 16; ++r)
    out[(size_t)(row0 + r)*UU + j] = acc[r];
}

// ---------- enc = speech @ Ua + Ua_b, stored bf16 [B][TE][U] ----------
__global__ __launch_bounds__(256) void enc_gemm(const float* __restrict__ speech,
    const float* __restrict__ Ua, const float* __restrict__ Uab,
    unsigned short* __restrict__ enc){
  __shared__ __align__(16) float aT[512*20];
  const int wg = blockIdx.x;
  const int b = wg >> 6, tb = (wg & 63) * 16;
  const int tid = threadIdx.x;
  const float* sp = speech + ((size_t)b*TE + tb)*EE;
  for (int it = 0; it < 32; ++it){
    int idx = tid + 256*it;
    int te = idx >> 9, e = idx & 511;
    aT[e*20 + te] = sp[(size_t)te*EE + e];
  }
  __syncthreads();
  const int j = tid;
  float bj = Uab[j];
  float acc[16];
  #pragma unroll
  for (int r = 0; r < 16; ++r) acc[r] = bj;
  const float* up = Ua + j;
  for (int e = 0; e < 512; ++e){
    float w = up[(size_t)e*UU];
    const float4* a4 = (const float4*)(aT + e*20);
    float4 q0 = a4[0], q1 = a4[1], q2 = a4[2], q3 = a4[3];
    acc[0]+=q0.x*w;  acc[1]+=q0.y*w;  acc[2]+=q0.z*w;  acc[3]+=q0.w*w;
    acc[4]+=q1.x*w;  acc[5]+=q1.y*w;  acc[6]+=q1.z*w;  acc[7]+=q1.w*w;
    acc[8]+=q2.x*w;  acc[9]+=q2.y*w;  acc[10]+=q2.z*w; acc[11]+=q2.w*w;
    acc[12]+=q3.x*w; acc[13]+=q3.y*w; acc[14]+=q3.z*w; acc[15]+=q3.w*w;
  }
  unsigned short* op = enc + ((size_t)b*TE + tb)*UU + j;
  #pragma unroll
  for (int r = 0; r < 16; ++r) op[(size_t)r*UU] = f2bf(acc[r]);
}

// ---------- persistent attention-LSTM scan ----------
// R9: 512 WGs x 512 threads, 8 WGs/batch (q8=bid&7 -> batch WGs span 8
//     XCDs; co-resident CU pair = two DIFFERENT batches). Confirmed:
//     floor 31.3->19.8 ms, VALUBusy 15.5->28%.
// R10 serial-tail cuts:
//  - flag-array barrier: per-WG flag word (plain relaxed store after
//    drain), poll = 8 lanes spin on 8 contiguous words (one coalesced L3
//    read). Replaces 8-way same-line atomic serialization, 2x per step.
//  - ctx merge via L3 accumulator: P3 partials atomicAdd into
//    ctx_acc[b][t&1][512] (L3-resident, double-buffered; q8==0 zeroes the
//    next buffer in the A-window) -> post-poll merge = 1 gload + 1 l-gload
//    per thread instead of 8+8.
//  - pf[16] full ctx-weight prefetch in the A-window -> post-merge
//    ctx-gate is pure LDS+VALU. Budget 128 VGPR (waves_per_eu(4,4));
//    FETCH_SIZE jump = spill tattletale.
__global__ __launch_bounds__(512)
__attribute__((amdgpu_waves_per_eu(4, 4)))
void scan_kernel(
    const float* __restrict__ x_seq, float* __restrict__ y_out,
    const unsigned short* __restrict__ enc, const unsigned short* __restrict__ speech,
    const unsigned short* __restrict__ KRP, const unsigned short* __restrict__ Wab,
    const float* __restrict__ Wa_b, const float* __restrict__ va,
    const float* __restrict__ gate_b,
    float* __restrict__ ctx_acc, float* __restrict__ l_acc, float* __restrict__ h_g,
    unsigned int* __restrict__ flg){
  extern __shared__ __align__(16) unsigned short enc_l[];   // [128][264] = 67.6 KB
  __shared__ float2 sva[256];        // (s[u], va[u])
  __shared__ float cat[1024];        // [0,256)=x_t  [256,768)=ctx  [768,1024)=h_{t-1}
  __shared__ float c_lds[32];
  __shared__ float lds_logit4[512];  // [4 u-quarters][128 te]
  __shared__ float p_lds[128];
  __shared__ float lds_pctx[512];
  __shared__ float zbuf[2][128];     // gate accumulators, ping-pong over t
  __shared__ float s_acc[256];
  __shared__ float red[16];
  __shared__ float nmi[2];

  const int tid = threadIdx.x;
  const int wg = blockIdx.x;
  const int b = wg >> 3, q8 = wg & 7;
  const int lane = tid & 63, wave = tid >> 6;
  unsigned int bar = 0;
  unsigned int* fbase = &flg[b*8];

  // one-time: stage this WG's enc slice (128 te x 256 u bf16) into LDS
  {
    const uint4* ep4 = (const uint4*)(enc + ((size_t)b*TE + q8*128)*UU);
    #pragma unroll
    for (int i = 0; i < 8; ++i){
      int idx = tid + 512*i;                    // 4096 uint4
      int te_l = idx >> 5, ch = idx & 31;
      uint4 v = ep4[(size_t)te_l*32 + ch];
      *(uint4*)(enc_l + (size_t)te_l*264 + ch*8) = v;
    }
  }
  if (tid < 256){ sva[tid] = make_float2(Wa_b[tid], va[tid]); cat[768 + tid] = 0.f; }
  if (tid < 128){ zbuf[0][tid] = 0.f; zbuf[1][tid] = 0.f; }
  if (tid < 32) c_lds[tid] = 0.f;
  if (tid >= 256 && tid < 512)
    cat[tid - 256] = x_seq[((size_t)b*TD + 0)*UU + (tid - 256)];
  __syncthreads();
  // prologue: x-rows gate contribution for t=0
  gate_accum8<8>(KRP, cat, zbuf[0], q8, 0, tid, lane);

  for (int t = 0; t < TD; ++t){
    // ---- loop top: zero scratch, issue x_{t+1} load (held in register) ----
    lds_pctx[tid] = 0.f;
    if (tid < 128) zbuf[(t+1)&1][tid] = 0.f;
    if (tid < 256) s_acc[tid] = 0.f;
    float xnext = 0.f;
    if (t < TD-1 && tid >= 256 && tid < 512)
      xnext = x_seq[((size_t)b*TD + t + 1)*UU + (tid - 256)];
    __syncthreads();

    // ---- P1: attention logits from LDS enc (conflict-free partial stores) ----
    {
      const int g = wave & 1, r = wave >> 1;
      const int te_l = g*64 + lane;             // local te 0..127
      const unsigned short* ep = enc_l + (size_t)te_l*264 + r*64;
      float acc = 0.f;
      #pragma unroll
      for (int c = 0; c < 8; ++c){
        uint4 v = *(const uint4*)(ep + c*8);
        const int ub = r*64 + c*8;
        unsigned int wv[4] = {v.x, v.y, v.z, v.w};
        #pragma unroll
        for (int i = 0; i < 4; ++i){
          float2 s0 = sva[ub + 2*i];
          float2 s1 = sva[ub + 2*i + 1];
          acc += s0.y * tanh_fast(s0.x + bflo(wv[i]));
          acc += s1.y * tanh_fast(s1.x + bfhi(wv[i]));
        }
      }
      lds_logit4[r*128 + te_l] = acc;           // unique (r,te_l) per thread
    }
    __syncthreads();

    // ---- P2: p = exp(logit), wave partial sums ----
    if (tid < 128){
      float lg = lds_logit4[tid] + lds_logit4[128 + tid]
               + lds_logit4[256 + tid] + lds_logit4[384 + tid];
      float p = fexp2(lg * 1.442695041f);
      p_lds[tid] = p;
      float s = p;
      #pragma unroll
      for (int o = 32; o > 0; o >>= 1) s += __shfl_xor(s, o);
      if (lane == 0) red[wave] = s;
    }
    __syncthreads();

    // ---- P3: partial ctx = sum_te p[te]*speech[te][:]  (uint4 stream) ----
    {
      const int c = tid & 63, tg = tid >> 6;    // e-chunk (8 e), te-group (16 te)
      const uint4* sp4 = (const uint4*)speech + ((size_t)b*TE + q8*128 + tg*16)*64 + c;
      float a0=0.f,a1=0.f,a2=0.f,a3=0.f,a4=0.f,a5=0.f,a6=0.f,a7=0.f;
      #pragma unroll 4
      for (int i = 0; i < 16; ++i){
        uint4 w = sp4[(size_t)i*64];
        float p = p_lds[tg*16 + i];
        a0 += p*bflo(w.x); a1 += p*bfhi(w.x);
        a2 += p*bflo(w.y); a3 += p*bfhi(w.y);
        a4 += p*bflo(w.z); a5 += p*bfhi(w.z);
        a6 += p*bflo(w.w); a7 += p*bfhi(w.w);
      }
      atomicAdd(&lds_pctx[c*8+0], a0); atomicAdd(&lds_pctx[c*8+1], a1);
      atomicAdd(&lds_pctx[c*8+2], a2); atomicAdd(&lds_pctx[c*8+3], a3);
      atomicAdd(&lds_pctx[c*8+4], a4); atomicAdd(&lds_pctx[c*8+5], a5);
      atomicAdd(&lds_pctx[c*8+6], a6); atomicAdd(&lds_pctx[c*8+7], a7);
    }
    __syncthreads();
    // export: device-scope f32 atomics into L3-resident accumulator
    atomicAdd(&ctx_acc[((size_t)b*2 + (t&1))*512 + tid], lds_pctx[tid]);
    if (tid == 0) atomicAdd(&l_acc[b*2 + (t&1)], red[0] + red[1]);
    drain_stores();
    __syncthreads();
    // ---- barrier A signal (per-WG flag; poll deferred) ----
    bar += 1;
    if (tid == 0) gstore_u(&fbase[q8], bar);

    // ---- A-window 1: gate h-rows (k 768..1023), needs only h_{t-1} ----
    gate_accum8<8>(KRP, cat, zbuf[t&1], q8, 768, tid, lane);

    // ---- A-window 2: zero next-step accumulators (q8==0 only) ----
    if (q8 == 0){
      gstore(&ctx_acc[((size_t)b*2 + ((t+1)&1))*512 + tid], 0.f);
      if (tid == 0) gstore(&l_acc[b*2 + ((t+1)&1)], 0.f);
    }

    // ---- A-window 3: prefetch ALL ctx-row weights into registers ----
    uint4 pf[16];
    {
      const int c = tid & 15, kg = tid >> 4;
      const uint4* kp = (const uint4*)KRP + ((size_t)q8*1024 + 256 + kg*16)*16 + c;
      #pragma unroll
      for (int i = 0; i < 16; ++i) pf[i] = kp[(size_t)i*16];
    }

    // ---- A-window 4: y_{t-1} = whatever_norm(h_{t-1}) (off critical path) ----
    if (t > 0){
      if (tid < 256){
        float hv = cat[768 + tid];
        float s1 = hv, s2 = hv*hv;
        #pragma unroll
        for (int o = 32; o > 0; o >>= 1){ s1 += __shfl_xor(s1, o); s2 += __shfl_xor(s2, o); }
        if (lane == 0){ red[wave*2] = s1; red[wave*2 + 1] = s2; }
      }
      __syncthreads();
      if (tid == 0){
        float m  = (red[0] + red[2] + red[4] + red[6]) * (1.f/256.f);
        float ms = (red[1] + red[3] + red[5] + red[7]) * (1.f/256.f);
        nmi[0] = m;
        nmi[1] = rsqrtf(ms - m*m + 1e-4f);
      }
      __syncthreads();
      if (tid < 32)
        y_out[((size_t)b*TD + (t-1))*UU + q8*32 + tid] =
            (cat[768 + q8*32 + tid] - nmi[0]) * nmi[1];
    }

    // ---- barrier A poll (8 lanes spin on 8 contiguous flags) ----
    if (tid < 8){
      while (gload_u(&fbase[tid]) < bar) __builtin_amdgcn_s_sleep(2);
    }
    __syncthreads();

    // ---- merge ctx: single accumulator load + l broadcast ----
    {
      float linv = frcp_(gload(&l_acc[b*2 + (t&1)]));
      cat[256 + tid] = gload(&ctx_acc[((size_t)b*2 + (t&1))*512 + tid]) * linv;
    }
    __syncthreads();

    // ---- gate ctx-rows (k 256..767) from prefetched registers ----
    {
      const int c = tid & 15, kg = tid >> 4;
      float a0=0.f,a1=0.f,a2=0.f,a3=0.f,a4=0.f,a5=0.f,a6=0.f,a7=0.f;
      #pragma unroll
      for (int i = 0; i < 16; ++i){
        uint4 w = pf[i];
        float ck = cat[256 + kg*16 + i];
        a0 += ck*bflo(w.x); a1 += ck*bfhi(w.x);
        a2 += ck*bflo(w.y); a3 += ck*bfhi(w.y);
        a4 += ck*bflo(w.z); a5 += ck*bfhi(w.z);
        a6 += ck*bflo(w.w); a7 += ck*bfhi(w.w);
      }
      a0 += __shfl_xor(a0, 16); a1 += __shfl_xor(a1, 16);
      a2 += __shfl_xor(a2, 16); a3 += __shfl_xor(a3, 16);
      a4 += __shfl_xor(a4, 16); a5 += __shfl_xor(a5, 16);
      a6 += __shfl_xor(a6, 16); a7 += __shfl_xor(a7, 16);
      a0 += __shfl_xor(a0, 32); a1 += __shfl_xor(a1, 32);
      a2 += __shfl_xor(a2, 32); a3 += __shfl_xor(a3, 32);
      a4 += __shfl_xor(a4, 32); a5 += __shfl_xor(a5, 32);
      a6 += __shfl_xor(a6, 32); a7 += __shfl_xor(a7, 32);
      float* zb = zbuf[t&1];
      if (lane < 16){
        atomicAdd(&zb[c*8+0], a0); atomicAdd(&zb[c*8+1], a1);
        atomicAdd(&zb[c*8+2], a2); atomicAdd(&zb[c*8+3], a3);
        atomicAdd(&zb[c*8+4], a4); atomicAdd(&zb[c*8+5], a5);
        atomicAdd(&zb[c*8+6], a6); atomicAdd(&zb[c*8+7], a7);
      }
    }
    __syncthreads();

    // ---- LSTM pointwise (keras i,f,g,o), export h slice ----
    if (tid < 32){
      const int jj = q8*32 + tid;
      const float* zb = zbuf[t&1];
      float zi = zb[tid]      + gate_b[jj];
      float zf = zb[32 + tid] + gate_b[256 + jj];
      float zg = zb[64 + tid] + gate_b[512 + jj];
      float zo = zb[96 + tid] + gate_b[768 + jj];
      float cn = sigmoid_fast(zf) * c_lds[tid] + sigmoid_fast(zi) * tanh_fast(zg);
      c_lds[tid] = cn;
      gstore(&h_g[(size_t)b*UU + jj], sigmoid_fast(zo) * tanh_fast(cn));
    }
    // park x_{t+1} (loaded at loop top) into cat[0..256)
    if (t < TD-1 && tid >= 256 && tid < 512) cat[tid - 256] = xnext;
    drain_stores();
    __syncthreads();
    // ---- barrier B signal (poll deferred: x-rows of t+1 hide it) ----
    bar += 1;
    if (tid == 0) gstore_u(&fbase[q8], bar);

    // ---- B-window: gate x-rows for t+1 (k 0..255), needs only x_{t+1} ----
    if (t < TD-1)
      gate_accum8<8>(KRP, cat, zbuf[(t+1)&1], q8, 0, tid, lane);

    // ---- barrier B poll ----
    if (tid < 8){
      while (gload_u(&fbase[tid]) < bar) __builtin_amdgcn_s_sleep(2);
    }
    __syncthreads();

    if (tid < 256) cat[768 + tid] = gload(&h_g[(size_t)b*UU + tid]);
    __syncthreads();

    // ---- s_{t+1} = h_t @ Wa + Wa_b (L2 stream; co-resident WG hides it) ----
    if (t < TD - 1){
      {
        const int c = tid & 31, kg = tid >> 5;  // u-chunk (8 u), kg in [0,16)
        const uint4* wp = (const uint4*)Wab + (size_t)(kg*16)*32 + c;
        float a0=0.f,a1=0.f,a2=0.f,a3=0.f,a4=0.f,a5=0.f,a6=0.f,a7=0.f;
        #pragma unroll 4
        for (int i = 0; i < 16; ++i){
          uint4 w = wp[(size_t)i*32];
          float hk = cat[768 + kg*16 + i];
          a0 += hk*bflo(w.x); a1 += hk*bfhi(w.x);
          a2 += hk*bflo(w.y); a3 += hk*bfhi(w.y);
          a4 += hk*bflo(w.z); a5 += hk*bfhi(w.z);
          a6 += hk*bflo(w.w); a7 += hk*bfhi(w.w);
        }
        a0 += __shfl_xor(a0, 32); a1 += __shfl_xor(a1, 32);
        a2 += __shfl_xor(a2, 32); a3 += __shfl_xor(a3, 32);
        a4 += __shfl_xor(a4, 32); a5 += __shfl_xor(a5, 32);
        a6 += __shfl_xor(a6, 32); a7 += __shfl_xor(a7, 32);
        if (lane < 32){
          atomicAdd(&s_acc[c*8+0], a0); atomicAdd(&s_acc[c*8+1], a1);
          atomicAdd(&s_acc[c*8+2], a2); atomicAdd(&s_acc[c*8+3], a3);
          atomicAdd(&s_acc[c*8+4], a4); atomicAdd(&s_acc[c*8+5], a5);
          atomicAdd(&s_acc[c*8+6], a6); atomicAdd(&s_acc[c*8+7], a7);
        }
      }
      __syncthreads();
      if (tid < 256) sva[tid].x = Wa_b[tid] + s_acc[tid];
    }
    __syncthreads();
  }

  // ---- epilogue: y_{TD-1} = whatever_norm(h_{TD-1}) ----
  {
    if (tid < 256){
      float hv = cat[768 + tid];
      float s1 = hv, s2 = hv*hv;
      #pragma unroll
      for (int o = 32; o > 0; o >>= 1){ s1 += __shfl_xor(s1, o); s2 += __shfl_xor(s2, o); }
      if (lane == 0){ red[wave*2] = s1; red[wave*2 + 1] = s2; }
    }
    __syncthreads();
    if (tid == 0){
      float m  = (red[0] + red[2] + red[4] + red[6]) * (1.f/256.f);
      float ms = (red[1] + red[3] + red[5] + red[7]) * (1.f/256.f);
      nmi[0] = m;
      nmi[1] = rsqrtf(ms - m*m + 1e-4f);
    }
    __syncthreads();
    if (tid < 32)
      y_out[((size_t)b*TD + (TD-1))*UU + q8*32 + tid] =
          (cat[768 + q8*32 + tid] - nmi[0]) * nmi[1];
  }
}

// ---------- head: norm(norm(y2@m1+b)@m2+b)@dW+db -> softmax ----------
__global__ __launch_bounds__(256) void head_kernel(const float* __restrict__ y2,
    const float* __restrict__ m1W, const float* __restrict__ m1b,
    const float* __restrict__ m2W, const float* __restrict__ m2b,
    const float* __restrict__ dW, const float* __restrict__ db,
    float* __restrict__ out){
  __shared__ __align__(16) float aT[256*20];
  __shared__ float t_lds[16*256];
  __shared__ float zl[16*64];
  __shared__ float mi[32];
  const int row0 = blockIdx.x * 16;
  const int tid = threadIdx.x;
  for (int it = 0; it < 16; ++it){
    int idx = tid + 256*it;
    int r = idx >> 8, k = idx & 255;
    aT[k*20 + r] = y2[(size_t)(row0 + r)*UU + k];
  }
  __syncthreads();

  #pragma unroll 1
  for (int pass = 0; pass < 2; ++pass){
    const float* Wp = pass ? m2W : m1W;
    const float* bp = pass ? m2b : m1b;
    const int j = tid;
    float bj = bp[j];
    float acc[16];
    #pragma unroll
    for (int r = 0; r < 16; ++r) acc[r] = bj;
    for (int k = 0; k < 256; ++k){
      float w = Wp[(size_t)k*UU + j];
      const float4* a4 = (const float4*)(aT + k*20);
      float4 q0 = a4[0], q1 = a4[1], q2 = a4[2], q3 = a4[3];
      acc[0]+=q0.x*w;  acc[1]+=q0.y*w;  acc[2]+=q0.z*w;  acc[3]+=q0.w*w;
      acc[4]+=q1.x*w;  acc[5]+=q1.y*w;  acc[6]+=q1.z*w;  acc[7]+=q1.w*w;
      acc[8]+=q2.x*w;  acc[9]+=q2.y*w;  acc[10]+=q2.z*w; acc[11]+=q2.w*w;
      acc[12]+=q3.x*w; acc[13]+=q3.y*w; acc[14]+=q3.z*w; acc[15]+=q3.w*w;
    }
    #pragma unroll
    for (int r = 0; r < 16; ++r) t_lds[r*256 + j] = acc[r];
    __syncthreads();
    {
      int r = tid >> 4, sg = tid & 15;
      float s1 = 0.f, s2 = 0.f;
      for (int c = 0; c < 16; ++c){
        float v = t_lds[r*256 + sg*16 + c];
        s1 += v; s2 += v*v;
      }
      for (int o = 1; o < 16; o <<= 1){ s1 += __shfl_xor(s1, o); s2 += __shfl_xor(s2, o); }
      if (sg == 0){
        float m = s1 * (1.f/256.f);
        float vv = s2 * (1.f/256.f) - m*m;
        mi[r*2] = m; mi[r*2+1] = rsqrtf(vv + 1e-4f);
      }
    }
    __syncthreads();
    {
      const int j2 = tid;
      #pragma unroll
      for (int r = 0; r < 16; ++r)
        aT[j2*20 + r] = (t_lds[r*256 + j2] - mi[r*2]) * mi[r*2+1];
    }
    __syncthreads();
  }

  for (int i = tid; i < 1024; i += 256) zl[i] = 0.f;
  __syncthreads();
  {
    const int j = tid & 63, kq = tid >> 6;
    float acc[16];
    #pragma unroll
    for (int r = 0; r < 16; ++r) acc[r] = 0.f;
    for (int k = 0; k < 64; ++k){
      float w = dW[(size_t)(kq*64 + k)*64 + j];
      const float4* a4 = (const float4*)(aT + (kq*64 + k)*20);
      float4 q0 = a4[0], q1 = a4[1], q2 = a4[2], q3 = a4[3];
      acc[0]+=q0.x*w;  acc[1]+=q0.y*w;  acc[2]+=q0.z*w;  acc[3]+=q0.w*w;
      acc[4]+=q1.x*w;  acc[5]+=q1.y*w;  acc[6]+=q1.z*w;  acc[7]+=q1.w*w;
      acc[8]+=q2.x*w;  acc[9]+=q2.y*w;  acc[10]+=q2.z*w; acc[11]+=q2.w*w;
      acc[12]+=q3.x*w; acc[13]+=q3.y*w; acc[14]+=q3.z*w; acc[15]+=q3.w*w;
    }
    #pragma unroll
    for (int r = 0; r < 16; ++r) atomicAdd(&zl[r*64 + j], acc[r]);
  }
  __syncthreads();
  if (tid < 16){
    const int r = tid;
    float mx = -1e30f;
    for (int j = 0; j < 64; ++j){ float v = zl[r*64 + j] + db[j]; zl[r*64 + j] = v; mx = fmaxf(mx, v); }
    float s = 0.f;
    for (int j = 0; j < 64; ++j){ float e = fexp2((zl[r*64 + j] - mx) * 1.442695041f); zl[r*64 + j] = e; s += e; }
    mi[r] = frcp_(s);
  }
  __syncthreads();
  for (int it = 0; it < 4; ++it){
    int idx = tid + 256*it;
    int r = idx >> 6, j = idx & 63;
    out[(size_t)(row0 + r)*64 + j] = zl[r*64 + j] * mi[r];
  }
}

// ---------- workspace layout (bytes) ----------
#define OFF_SPEECH 0u
#define OFF_ENC    67108864u
#define OFF_KR     100663296u
#define OFF_WA     102760448u
#define OFF_X1     102891520u
#define OFF_Y1     136445952u
#define OFF_PCTX   170000384u   // ctx_acc: 64*2*512*4 = 262144 B
#define OFF_LACC   170262528u   // l_acc:   64*2*4     = 512 B
#define OFF_H      171051008u   // 64 KB
#define OFF_CTR    171116544u   // flags: 64*8*4 = 2 KB (4 KB reserved)

#define DYN_LDS    67584    // 128 rows x 264 ushorts

extern "C" void kernel_launch(void* const* d_in, const int* in_sizes, int n_in,
                              void* d_out, int out_size, void* d_ws, size_t ws_size,
                              hipStream_t stream){
  const float* trans  = (const float*)d_in[0];
  const float* speech = (const float*)d_in[1];
  const float* emb_W  = (const float*)d_in[2];
  const float* emb_b  = (const float*)d_in[3];
  const float* Ua_W[2]  = {(const float*)d_in[4],  (const float*)d_in[13]};
  const float* Ua_b[2]  = {(const float*)d_in[5],  (const float*)d_in[14]};
  const float* Wa_W[2]  = {(const float*)d_in[6],  (const float*)d_in[15]};
  const float* Wa_bv[2] = {(const float*)d_in[7],  (const float*)d_in[16]};
  const float* va_W[2]  = {(const float*)d_in[8],  (const float*)d_in[17]};
  // d_in[9]/d_in[18] = va_b: constant logit shift, softmax-invariant, dropped exactly.
  const float* Kw[2]    = {(const float*)d_in[10], (const float*)d_in[19]};
  const float* Rw[2]    = {(const float*)d_in[11], (const float*)d_in[20]};
  const float* bw[2]    = {(const float*)d_in[12], (const float*)d_in[21]};
  const float* m1W = (const float*)d_in[22];
  const float* m1b = (const float*)d_in[23];
  const float* m2W = (const float*)d_in[24];
  const float* m2b = (const float*)d_in[25];
  const float* dW  = (const float*)d_in[26];
  const float* db  = (const float*)d_in[27];

  char* ws = (char*)d_ws;
  unsigned short* speech_bf = (unsigned short*)(ws + OFF_SPEECH);
  unsigned short* enc  = (unsigned short*)(ws + OFF_ENC);
  unsigned short* KRP  = (unsigned short*)(ws + OFF_KR);
  unsigned short* Wab  = (unsigned short*)(ws + OFF_WA);
  float* x1   = (float*)(ws + OFF_X1);
  float* y1   = (float*)(ws + OFF_Y1);
  float* ctxa = (float*)(ws + OFF_PCTX);
  float* lacc = (float*)(ws + OFF_LACC);
  float* hg   = (float*)(ws + OFF_H);
  unsigned int* flg = (unsigned int*)(ws + OFF_CTR);
  float* y2 = x1;   // x1 dead after scan1 consumes it

  hipFuncSetAttribute((const void*)scan_kernel,
                      hipFuncAttributeMaxDynamicSharedMemorySize, DYN_LDS);

  pack_bf16v<<<4096, 256, 0, stream>>>(speech, speech_bf, B*TE*EE/4);
  emb_gemm<<<2048, 256, 0, stream>>>(trans, emb_W, emb_b, x1);

  for (int L = 0; L < 2; ++L){
    enc_gemm<<<4096, 256, 0, stream>>>(speech, Ua_W[L], Ua_b[L], enc);
    pack_KRP<<<4096, 256, 0, stream>>>(Kw[L], Rw[L], KRP);
    pack_bf16v<<<64, 256, 0, stream>>>(Wa_W[L], Wab, UU*UU/4);
    hipMemsetAsync(flg, 0, 4096, stream);
    hipMemsetAsync(ctxa, 0, 262656, stream);   // ctx_acc + l_acc (contiguous)
    scan_kernel<<<512, 512, DYN_LDS, stream>>>(L == 0 ? x1 : y1, L == 0 ? y1 : y2,
        enc, speech_bf, KRP, Wab, Wa_bv[L], va_W[L], bw[L], ctxa, lacc, hg, flg);
  }

  head_kernel<<<2048, 256, 0, stream>>>(y2, m1W, m1b, m2W, m2b, dW, db, (float*)d_out);
  (void)in_sizes; (void)n_in; (void)out_size; (void)ws_size;
}

// Round 7
// 39753.421 us; speedup vs baseline: 1.6083x; 1.6083x over previous
//
#include <hip/hip_runtime.h>
#include <hip/hip_bf16.h>
#include <stdint.h>

#define B  64
#define TD 512
#define TE 1024
#define EE 512
#define UU 256

// ---------- numeric helpers ----------
__device__ __forceinline__ float fexp2(float x){ return __builtin_amdgcn_exp2f(x); }
__device__ __forceinline__ float frcp_(float x){ return __builtin_amdgcn_rcpf(x); }
__device__ __forceinline__ float tanh_fast(float x){
  float e = fexp2(x * 2.885390082f);
  return 1.f - 2.f * frcp_(e + 1.f);
}
__device__ __forceinline__ float sigmoid_fast(float x){
  return frcp_(1.f + fexp2(-1.442695041f * x));
}
__device__ __forceinline__ unsigned short f2bf(float f){
  unsigned int u = __float_as_uint(f);
  u = (u + 0x7fffu + ((u >> 16) & 1u)) >> 16;   // RNE
  return (unsigned short)u;
}
__device__ __forceinline__ float bflo(unsigned int w){ return __uint_as_float(w << 16); }
__device__ __forceinline__ float bfhi(unsigned int w){ return __uint_as_float(w & 0xffff0000u); }

// Cross-XCD comm WITHOUT cache flushes: relaxed system-scope ops lower to
// global_load/store/atomic with sc0 sc1 (bypass L1/L2, coherent at L3) and
// never emit buffer_inv/buffer_wbl2 -> L2 stays hot for speech/KRP.
__device__ __forceinline__ void gstore(float* p, float v){
  __hip_atomic_store(p, v, __ATOMIC_RELAXED, __HIP_MEMORY_SCOPE_SYSTEM);
}
__device__ __forceinline__ float gload(const float* p){
  return __hip_atomic_load(p, __ATOMIC_RELAXED, __HIP_MEMORY_SCOPE_SYSTEM);
}
__device__ __forceinline__ void gstore_u(unsigned int* p, unsigned int v){
  __hip_atomic_store(p, v, __ATOMIC_RELAXED, __HIP_MEMORY_SCOPE_SYSTEM);
}
__device__ __forceinline__ unsigned int gload_u(const unsigned int* p){
  return __hip_atomic_load(p, __ATOMIC_RELAXED, __HIP_MEMORY_SCOPE_SYSTEM);
}
__device__ __forceinline__ void drain_stores(){
  __atomic_signal_fence(__ATOMIC_SEQ_CST);
  __builtin_amdgcn_s_waitcnt(0);
  __atomic_signal_fence(__ATOMIC_SEQ_CST);
}

// Gate partial GEMV (512-thread WG, 128 output columns) over k-range
// [k0, k0+32*NITER). c = j-chunk (8 of 128 cols), kg = k-group. Lanes
// {l, l+16, l+32, l+48} share c -> 2-step shfl reduce, lane<16 atomics.
template<int NITER>
__device__ __forceinline__ void gate_accum8(const unsigned short* __restrict__ KRP,
    const float* catp, float* zb, int q8, int k0, int tid, int lane){
  const int c = tid & 15, kg = tid >> 4;     // kg in [0,32)
  const uint4* kp = (const uint4*)KRP + ((size_t)q8*1024 + k0 + kg*NITER)*16 + c;
  float a0=0.f,a1=0.f,a2=0.f,a3=0.f,a4=0.f,a5=0.f,a6=0.f,a7=0.f;
  #pragma unroll 4
  for (int i = 0; i < NITER; ++i){
    uint4 w = kp[(size_t)i*16];
    float ck = catp[k0 + kg*NITER + i];
    a0 += ck*bflo(w.x); a1 += ck*bfhi(w.x);
    a2 += ck*bflo(w.y); a3 += ck*bfhi(w.y);
    a4 += ck*bflo(w.z); a5 += ck*bfhi(w.z);
    a6 += ck*bflo(w.w); a7 += ck*bfhi(w.w);
  }
  a0 += __shfl_xor(a0, 16); a1 += __shfl_xor(a1, 16);
  a2 += __shfl_xor(a2, 16); a3 += __shfl_xor(a3, 16);
  a4 += __shfl_xor(a4, 16); a5 += __shfl_xor(a5, 16);
  a6 += __shfl_xor(a6, 16); a7 += __shfl_xor(a7, 16);
  a0 += __shfl_xor(a0, 32); a1 += __shfl_xor(a1, 32);
  a2 += __shfl_xor(a2, 32); a3 += __shfl_xor(a3, 32);
  a4 += __shfl_xor(a4, 32); a5 += __shfl_xor(a5, 32);
  a6 += __shfl_xor(a6, 32); a7 += __shfl_xor(a7, 32);
  if (lane < 16){
    atomicAdd(&zb[c*8+0], a0); atomicAdd(&zb[c*8+1], a1);
    atomicAdd(&zb[c*8+2], a2); atomicAdd(&zb[c*8+3], a3);
    atomicAdd(&zb[c*8+4], a4); atomicAdd(&zb[c*8+5], a5);
    atomicAdd(&zb[c*8+6], a6); atomicAdd(&zb[c*8+7], a7);
  }
}

// ---------- pack kernels ----------
__global__ void pack_bf16v(const float* __restrict__ in, unsigned short* __restrict__ out, int n4){
  int i = blockIdx.x * blockDim.x + threadIdx.x;
  int stride = gridDim.x * blockDim.x;
  for (; i < n4; i += stride){
    float4 v = ((const float4*)in)[i];
    ushort4 o;
    o.x = f2bf(v.x); o.y = f2bf(v.y); o.z = f2bf(v.z); o.w = f2bf(v.w);
    ((ushort4*)out)[i] = o;
  }
}

// KRP[q8][k][jj]: per-WG-contiguous gate weights for 8 WGs/batch. jj in
// [0,128) maps to logical column J = (jj>>5)*256 + q8*32 + (jj&31);
// rows 0..767 = K, 768..1023 = R. Total 8*1024*128 = 1,048,576 elements
// -> grid MUST be 4096 x 256 exactly.
__global__ void pack_KRP(const float* __restrict__ K, const float* __restrict__ R,
                         unsigned short* __restrict__ KRP){
  int idx = blockIdx.x * 256 + threadIdx.x;    // 4096 blocks -> 1M exactly
  int q8 = idx >> 17;
  int k  = (idx >> 7) & 1023;
  int jj = idx & 127;
  int J  = (jj >> 5)*256 + q8*32 + (jj & 31);
  float v = (k < 768) ? K[(size_t)k*1024 + J] : R[(size_t)(k - 768)*1024 + J];
  KRP[idx] = f2bf(v);
}

// ---------- secrets = trans @ emb_W + emb_b : [32768,64]@[64,256] ----------
__global__ __launch_bounds__(256) void emb_gemm(const float* __restrict__ trans,
    const float* __restrict__ W, const float* __restrict__ bias, float* __restrict__ out){
  __shared__ __align__(16) float aT[64*20];
  const int row0 = blockIdx.x * 16;
  const int tid = threadIdx.x;
  {
    int r = tid >> 6, k = tid & 63;
    for (int rr = r; rr < 16; rr += 4)
      aT[k*20 + rr] = trans[(size_t)(row0 + rr)*64 + k];
  }
  __syncthreads();
  const int j = tid;
  float bj = bias[j];
  float acc[16];
  #pragma unroll
  for (int r = 0; r < 16; ++r) acc[r] = bj;
  for (int k = 0; k < 64; ++k){
    float w = W[(size_t)k*UU + j];
    const float4* a4 = (const float4*)(aT + k*20);
    float4 q0 = a4[0], q1 = a4[1], q2 = a4[2], q3 = a4[3];
    acc[0]+=q0.x*w;  acc[1]+=q0.y*w;  acc[2]+=q0.z*w;  acc[3]+=q0.w*w;
    acc[4]+=q1.x*w;  acc[5]+=q1.y*w;  acc[6]+=q1.z*w;  acc[7]+=q1.w*w;
    acc[8]+=q2.x*w;  acc[9]+=q2.y*w;  acc[10]+=q2.z*w; acc[11]+=q2.w*w;
    acc[12]+=q3.x*w; acc[13]+=q3.y*w; acc[14]+=q3.z*w; acc[15]+=q3.w*w;
  }
  #pragma unroll
  for (int r = 0; r < 16; ++r)
    out[(size_t)(row0 + r)*UU + j] = acc[r];
}

// ---------- enc = speech @ Ua + Ua_b, stored bf16 [B][TE][U] ----------
__global__ __launch_bounds__(256) void enc_gemm(const float* __restrict__ speech,
    const float* __restrict__ Ua, const float* __restrict__ Uab,
    unsigned short* __restrict__ enc){
  __shared__ __align__(16) float aT[512*20];
  const int wg = blockIdx.x;
  const int b = wg >> 6, tb = (wg & 63) * 16;
  const int tid = threadIdx.x;
  const float* sp = speech + ((size_t)b*TE + tb)*EE;
  for (int it = 0; it < 32; ++it){
    int idx = tid + 256*it;
    int te = idx >> 9, e = idx & 511;
    aT[e*20 + te] = sp[(size_t)te*EE + e];
  }
  __syncthreads();
  const int j = tid;
  float bj = Uab[j];
  float acc[16];
  #pragma unroll
  for (int r = 0; r < 16; ++r) acc[r] = bj;
  const float* up = Ua + j;
  for (int e = 0; e < 512; ++e){
    float w = up[(size_t)e*UU];
    const float4* a4 = (const float4*)(aT + e*20);
    float4 q0 = a4[0], q1 = a4[1], q2 = a4[2], q3 = a4[3];
    acc[0]+=q0.x*w;  acc[1]+=q0.y*w;  acc[2]+=q0.z*w;  acc[3]+=q0.w*w;
    acc[4]+=q1.x*w;  acc[5]+=q1.y*w;  acc[6]+=q1.z*w;  acc[7]+=q1.w*w;
    acc[8]+=q2.x*w;  acc[9]+=q2.y*w;  acc[10]+=q2.z*w; acc[11]+=q2.w*w;
    acc[12]+=q3.x*w; acc[13]+=q3.y*w; acc[14]+=q3.z*w; acc[15]+=q3.w*w;
  }
  unsigned short* op = enc + ((size_t)b*TE + tb)*UU + j;
  #pragma unroll
  for (int r = 0; r < 16; ++r) op[(size_t)r*UU] = f2bf(acc[r]);
}

// ---------- persistent attention-LSTM scan ----------
// R9: 512 WGs x 512 threads, 8 WGs/batch (q8=bid&7), 2 WGs (different
//     batches) co-resident per CU. Floor 31.3->19.8 ms, VALUBusy 28%.
// R10 FAILED (partially): pf[16] ctx-weight prefetch spilled again
//     (VGPR cap is empirically stuck at 64 across launch_bounds(.,4) and
//     waves_per_eu(4,4) attempts; FETCH +17.3 GB, floor 30 ms). Lesson:
//     design within 64 VGPRs — no register-resident weight blocks.
// R11 = R9 + register-free R10 wins only:
//  - flag-array barrier: per-WG flag word (relaxed store after drain),
//    poll = 8 lanes spin on 8 contiguous words (coalesced L3 read).
//  - ctx merge via L3 accumulator: P3 partials atomicAdd into
//    ctx_acc[b][t&1][512] (double-buffered; q8==0 zeroes next buffer in
//    the A-window) -> post-poll merge = 1 gload + 1 l-gload per thread.
//  - ctx-gate reverted to plain L2 uint4 stream (fits 64-reg budget).
__global__ __launch_bounds__(512)
__attribute__((amdgpu_waves_per_eu(4, 4)))
void scan_kernel(
    const float* __restrict__ x_seq, float* __restrict__ y_out,
    const unsigned short* __restrict__ enc, const unsigned short* __restrict__ speech,
    const unsigned short* __restrict__ KRP, const unsigned short* __restrict__ Wab,
    const float* __restrict__ Wa_b, const float* __restrict__ va,
    const float* __restrict__ gate_b,
    float* __restrict__ ctx_acc, float* __restrict__ l_acc, float* __restrict__ h_g,
    unsigned int* __restrict__ flg){
  extern __shared__ __align__(16) unsigned short enc_l[];   // [128][264] = 67.6 KB
  __shared__ float2 sva[256];        // (s[u], va[u])
  __shared__ float cat[1024];        // [0,256)=x_t  [256,768)=ctx  [768,1024)=h_{t-1}
  __shared__ float c_lds[32];
  __shared__ float lds_logit4[512];  // [4 u-quarters][128 te]
  __shared__ float p_lds[128];
  __shared__ float lds_pctx[512];
  __shared__ float zbuf[2][128];     // gate accumulators, ping-pong over t
  __shared__ float s_acc[256];
  __shared__ float red[16];
  __shared__ float nmi[2];

  const int tid = threadIdx.x;
  const int wg = blockIdx.x;
  const int b = wg >> 3, q8 = wg & 7;
  const int lane = tid & 63, wave = tid >> 6;
  unsigned int bar = 0;
  unsigned int* fbase = &flg[b*8];

  // one-time: stage this WG's enc slice (128 te x 256 u bf16) into LDS
  {
    const uint4* ep4 = (const uint4*)(enc + ((size_t)b*TE + q8*128)*UU);
    #pragma unroll
    for (int i = 0; i < 8; ++i){
      int idx = tid + 512*i;                    // 4096 uint4
      int te_l = idx >> 5, ch = idx & 31;
      uint4 v = ep4[(size_t)te_l*32 + ch];
      *(uint4*)(enc_l + (size_t)te_l*264 + ch*8) = v;
    }
  }
  if (tid < 256){ sva[tid] = make_float2(Wa_b[tid], va[tid]); cat[768 + tid] = 0.f; }
  if (tid < 128){ zbuf[0][tid] = 0.f; zbuf[1][tid] = 0.f; }
  if (tid < 32) c_lds[tid] = 0.f;
  if (tid >= 256 && tid < 512)
    cat[tid - 256] = x_seq[((size_t)b*TD + 0)*UU + (tid - 256)];
  __syncthreads();
  // prologue: x-rows gate contribution for t=0
  gate_accum8<8>(KRP, cat, zbuf[0], q8, 0, tid, lane);

  for (int t = 0; t < TD; ++t){
    // ---- loop top: zero scratch, issue x_{t+1} load (held in register) ----
    lds_pctx[tid] = 0.f;
    if (tid < 128) zbuf[(t+1)&1][tid] = 0.f;
    if (tid < 256) s_acc[tid] = 0.f;
    float xnext = 0.f;
    if (t < TD-1 && tid >= 256 && tid < 512)
      xnext = x_seq[((size_t)b*TD + t + 1)*UU + (tid - 256)];
    __syncthreads();

    // ---- P1: attention logits from LDS enc (conflict-free partial stores) ----
    {
      const int g = wave & 1, r = wave >> 1;
      const int te_l = g*64 + lane;             // local te 0..127
      const unsigned short* ep = enc_l + (size_t)te_l*264 + r*64;
      float acc = 0.f;
      #pragma unroll
      for (int c = 0; c < 8; ++c){
        uint4 v = *(const uint4*)(ep + c*8);
        const int ub = r*64 + c*8;
        unsigned int wv[4] = {v.x, v.y, v.z, v.w};
        #pragma unroll
        for (int i = 0; i < 4; ++i){
          float2 s0 = sva[ub + 2*i];
          float2 s1 = sva[ub + 2*i + 1];
          acc += s0.y * tanh_fast(s0.x + bflo(wv[i]));
          acc += s1.y * tanh_fast(s1.x + bfhi(wv[i]));
        }
      }
      lds_logit4[r*128 + te_l] = acc;           // unique (r,te_l) per thread
    }
    __syncthreads();

    // ---- P2: p = exp(logit), wave partial sums ----
    if (tid < 128){
      float lg = lds_logit4[tid] + lds_logit4[128 + tid]
               + lds_logit4[256 + tid] + lds_logit4[384 + tid];
      float p = fexp2(lg * 1.442695041f);
      p_lds[tid] = p;
      float s = p;
      #pragma unroll
      for (int o = 32; o > 0; o >>= 1) s += __shfl_xor(s, o);
      if (lane == 0) red[wave] = s;
    }
    __syncthreads();

    // ---- P3: partial ctx = sum_te p[te]*speech[te][:]  (uint4 stream) ----
    {
      const int c = tid & 63, tg = tid >> 6;    // e-chunk (8 e), te-group (16 te)
      const uint4* sp4 = (const uint4*)speech + ((size_t)b*TE + q8*128 + tg*16)*64 + c;
      float a0=0.f,a1=0.f,a2=0.f,a3=0.f,a4=0.f,a5=0.f,a6=0.f,a7=0.f;
      #pragma unroll 4
      for (int i = 0; i < 16; ++i){
        uint4 w = sp4[(size_t)i*64];
        float p = p_lds[tg*16 + i];
        a0 += p*bflo(w.x); a1 += p*bfhi(w.x);
        a2 += p*bflo(w.y); a3 += p*bfhi(w.y);
        a4 += p*bflo(w.z); a5 += p*bfhi(w.z);
        a6 += p*bflo(w.w); a7 += p*bfhi(w.w);
      }
      atomicAdd(&lds_pctx[c*8+0], a0); atomicAdd(&lds_pctx[c*8+1], a1);
      atomicAdd(&lds_pctx[c*8+2], a2); atomicAdd(&lds_pctx[c*8+3], a3);
      atomicAdd(&lds_pctx[c*8+4], a4); atomicAdd(&lds_pctx[c*8+5], a5);
      atomicAdd(&lds_pctx[c*8+6], a6); atomicAdd(&lds_pctx[c*8+7], a7);
    }
    __syncthreads();
    // export: device-scope f32 atomics into L3-resident accumulator
    atomicAdd(&ctx_acc[((size_t)b*2 + (t&1))*512 + tid], lds_pctx[tid]);
    if (tid == 0) atomicAdd(&l_acc[b*2 + (t&1)], red[0] + red[1]);
    drain_stores();
    __syncthreads();
    // ---- barrier A signal (per-WG flag; poll deferred) ----
    bar += 1;
    if (tid == 0) gstore_u(&fbase[q8], bar);

    // ---- A-window 1: gate h-rows (k 768..1023), needs only h_{t-1} ----
    gate_accum8<8>(KRP, cat, zbuf[t&1], q8, 768, tid, lane);

    // ---- A-window 2: zero next-step accumulators (q8==0 only) ----
    if (q8 == 0){
      gstore(&ctx_acc[((size_t)b*2 + ((t+1)&1))*512 + tid], 0.f);
      if (tid == 0) gstore(&l_acc[b*2 + ((t+1)&1)], 0.f);
    }

    // ---- A-window 3: y_{t-1} = whatever_norm(h_{t-1}) (off critical path;
    //      all WGs reduce redundantly, each writes its own 32-wide slice) ----
    if (t > 0){
      if (tid < 256){
        float hv = cat[768 + tid];
        float s1 = hv, s2 = hv*hv;
        #pragma unroll
        for (int o = 32; o > 0; o >>= 1){ s1 += __shfl_xor(s1, o); s2 += __shfl_xor(s2, o); }
        if (lane == 0){ red[wave*2] = s1; red[wave*2 + 1] = s2; }
      }
      __syncthreads();
      if (tid == 0){
        float m  = (red[0] + red[2] + red[4] + red[6]) * (1.f/256.f);
        float ms = (red[1] + red[3] + red[5] + red[7]) * (1.f/256.f);
        nmi[0] = m;
        nmi[1] = rsqrtf(ms - m*m + 1e-4f);
      }
      __syncthreads();
      if (tid < 32)
        y_out[((size_t)b*TD + (t-1))*UU + q8*32 + tid] =
            (cat[768 + q8*32 + tid] - nmi[0]) * nmi[1];
    }

    // ---- barrier A poll (8 lanes spin on 8 contiguous flags) ----
    if (tid < 8){
      while (gload_u(&fbase[tid]) < bar) __builtin_amdgcn_s_sleep(2);
    }
    __syncthreads();

    // ---- merge ctx: single accumulator load + l broadcast ----
    {
      float linv = frcp_(gload(&l_acc[b*2 + (t&1)]));
      cat[256 + tid] = gload(&ctx_acc[((size_t)b*2 + (t&1))*512 + tid]) * linv;
    }
    __syncthreads();

    // ---- gate ctx-rows (k 256..767): 16-iter uint4 L2 stream ----
    gate_accum8<16>(KRP, cat, zbuf[t&1], q8, 256, tid, lane);
    __syncthreads();

    // ---- LSTM pointwise (keras i,f,g,o), export h slice ----
    if (tid < 32){
      const int jj = q8*32 + tid;
      const float* zb = zbuf[t&1];
      float zi = zb[tid]      + gate_b[jj];
      float zf = zb[32 + tid] + gate_b[256 + jj];
      float zg = zb[64 + tid] + gate_b[512 + jj];
      float zo = zb[96 + tid] + gate_b[768 + jj];
      float cn = sigmoid_fast(zf) * c_lds[tid] + sigmoid_fast(zi) * tanh_fast(zg);
      c_lds[tid] = cn;
      gstore(&h_g[(size_t)b*UU + jj], sigmoid_fast(zo) * tanh_fast(cn));
    }
    // park x_{t+1} (loaded at loop top) into cat[0..256)
    if (t < TD-1 && tid >= 256 && tid < 512) cat[tid - 256] = xnext;
    drain_stores();
    __syncthreads();
    // ---- barrier B signal (poll deferred: x-rows of t+1 hide it) ----
    bar += 1;
    if (tid == 0) gstore_u(&fbase[q8], bar);

    // ---- B-window: gate x-rows for t+1 (k 0..255), needs only x_{t+1} ----
    if (t < TD-1)
      gate_accum8<8>(KRP, cat, zbuf[(t+1)&1], q8, 0, tid, lane);

    // ---- barrier B poll ----
    if (tid < 8){
      while (gload_u(&fbase[tid]) < bar) __builtin_amdgcn_s_sleep(2);
    }
    __syncthreads();

    if (tid < 256) cat[768 + tid] = gload(&h_g[(size_t)b*UU + tid]);
    __syncthreads();

    // ---- s_{t+1} = h_t @ Wa + Wa_b (L2 stream; co-resident WG hides it) ----
    if (t < TD - 1){
      {
        const int c = tid & 31, kg = tid >> 5;  // u-chunk (8 u), kg in [0,16)
        const uint4* wp = (const uint4*)Wab + (size_t)(kg*16)*32 + c;
        float a0=0.f,a1=0.f,a2=0.f,a3=0.f,a4=0.f,a5=0.f,a6=0.f,a7=0.f;
        #pragma unroll 4
        for (int i = 0; i < 16; ++i){
          uint4 w = wp[(size_t)i*32];
          float hk = cat[768 + kg*16 + i];
          a0 += hk*bflo(w.x); a1 += hk*bfhi(w.x);
          a2 += hk*bflo(w.y); a3 += hk*bfhi(w.y);
          a4 += hk*bflo(w.z); a5 += hk*bfhi(w.z);
          a6 += hk*bflo(w.w); a7 += hk*bfhi(w.w);
        }
        a0 += __shfl_xor(a0, 32); a1 += __shfl_xor(a1, 32);
        a2 += __shfl_xor(a2, 32); a3 += __shfl_xor(a3, 32);
        a4 += __shfl_xor(a4, 32); a5 += __shfl_xor(a5, 32);
        a6 += __shfl_xor(a6, 32); a7 += __shfl_xor(a7, 32);
        if (lane < 32){
          atomicAdd(&s_acc[c*8+0], a0); atomicAdd(&s_acc[c*8+1], a1);
          atomicAdd(&s_acc[c*8+2], a2); atomicAdd(&s_acc[c*8+3], a3);
          atomicAdd(&s_acc[c*8+4], a4); atomicAdd(&s_acc[c*8+5], a5);
          atomicAdd(&s_acc[c*8+6], a6); atomicAdd(&s_acc[c*8+7], a7);
        }
      }
      __syncthreads();
      if (tid < 256) sva[tid].x = Wa_b[tid] + s_acc[tid];
    }
    __syncthreads();
  }

  // ---- epilogue: y_{TD-1} = whatever_norm(h_{TD-1}) ----
  {
    if (tid < 256){
      float hv = cat[768 + tid];
      float s1 = hv, s2 = hv*hv;
      #pragma unroll
      for (int o = 32; o > 0; o >>= 1){ s1 += __shfl_xor(s1, o); s2 += __shfl_xor(s2, o); }
      if (lane == 0){ red[wave*2] = s1; red[wave*2 + 1] = s2; }
    }
    __syncthreads();
    if (tid == 0){
      float m  = (red[0] + red[2] + red[4] + red[6]) * (1.f/256.f);
      float ms = (red[1] + red[3] + red[5] + red[7]) * (1.f/256.f);
      nmi[0] = m;
      nmi[1] = rsqrtf(ms - m*m + 1e-4f);
    }
    __syncthreads();
    if (tid < 32)
      y_out[((size_t)b*TD + (TD-1))*UU + q8*32 + tid] =
          (cat[768 + q8*32 + tid] - nmi[0]) * nmi[1];
  }
}

// ---------- head: norm(norm(y2@m1+b)@m2+b)@dW+db -> softmax ----------
__global__ __launch_bounds__(256) void head_kernel(const float* __restrict__ y2,
    const float* __restrict__ m1W, const float* __restrict__ m1b,
    const float* __restrict__ m2W, const float* __restrict__ m2b,
    const float* __restrict__ dW, const float* __restrict__ db,
    float* __restrict__ out){
  __shared__ __align__(16) float aT[256*20];
  __shared__ float t_lds[16*256];
  __shared__ float zl[16*64];
  __shared__ float mi[32];
  const int row0 = blockIdx.x * 16;
  const int tid = threadIdx.x;
  for (int it = 0; it < 16; ++it){
    int idx = tid + 256*it;
    int r = idx >> 8, k = idx & 255;
    aT[k*20 + r] = y2[(size_t)(row0 + r)*UU + k];
  }
  __syncthreads();

  #pragma unroll 1
  for (int pass = 0; pass < 2; ++pass){
    const float* Wp = pass ? m2W : m1W;
    const float* bp = pass ? m2b : m1b;
    const int j = tid;
    float bj = bp[j];
    float acc[16];
    #pragma unroll
    for (int r = 0; r < 16; ++r) acc[r] = bj;
    for (int k = 0; k < 256; ++k){
      float w = Wp[(size_t)k*UU + j];
      const float4* a4 = (const float4*)(aT + k*20);
      float4 q0 = a4[0], q1 = a4[1], q2 = a4[2], q3 = a4[3];
      acc[0]+=q0.x*w;  acc[1]+=q0.y*w;  acc[2]+=q0.z*w;  acc[3]+=q0.w*w;
      acc[4]+=q1.x*w;  acc[5]+=q1.y*w;  acc[6]+=q1.z*w;  acc[7]+=q1.w*w;
      acc[8]+=q2.x*w;  acc[9]+=q2.y*w;  acc[10]+=q2.z*w; acc[11]+=q2.w*w;
      acc[12]+=q3.x*w; acc[13]+=q3.y*w; acc[14]+=q3.z*w; acc[15]+=q3.w*w;
    }
    #pragma unroll
    for (int r = 0; r < 16; ++r) t_lds[r*256 + j] = acc[r];
    __syncthreads();
    {
      int r = tid >> 4, sg = tid & 15;
      float s1 = 0.f, s2 = 0.f;
      for (int c = 0; c < 16; ++c){
        float v = t_lds[r*256 + sg*16 + c];
        s1 += v; s2 += v*v;
      }
      for (int o = 1; o < 16; o <<= 1){ s1 += __shfl_xor(s1, o); s2 += __shfl_xor(s2, o); }
      if (sg == 0){
        float m = s1 * (1.f/256.f);
        float vv = s2 * (1.f/256.f) - m*m;
        mi[r*2] = m; mi[r*2+1] = rsqrtf(vv + 1e-4f);
      }
    }
    __syncthreads();
    {
      const int j2 = tid;
      #pragma unroll
      for (int r = 0; r < 16; ++r)
        aT[j2*20 + r] = (t_lds[r*256 + j2] - mi[r*2]) * mi[r*2+1];
    }
    __syncthreads();
  }

  for (int i = tid; i < 1024; i += 256) zl[i] = 0.f;
  __syncthreads();
  {
    const int j = tid & 63, kq = tid >> 6;
    float acc[16];
    #pragma unroll
    for (int r = 0; r < 16; ++r) acc[r] = 0.f;
    for (int k = 0; k < 64; ++k){
      float w = dW[(size_t)(kq*64 + k)*64 + j];
      const float4* a4 = (const float4*)(aT + (kq*64 + k)*20);
      float4 q0 = a4[0], q1 = a4[1], q2 = a4[2], q3 = a4[3];
      acc[0]+=q0.x*w;  acc[1]+=q0.y*w;  acc[2]+=q0.z*w;  acc[3]+=q0.w*w;
      acc[4]+=q1.x*w;  acc[5]+=q1.y*w;  acc[6]+=q1.z*w;  acc[7]+=q1.w*w;
      acc[8]+=q2.x*w;  acc[9]+=q2.y*w;  acc[10]+=q2.z*w; acc[11]+=q2.w*w;
      acc[12]+=q3.x*w; acc[13]+=q3.y*w; acc[14]+=q3.z*w; acc[15]+=q3.w*w;
    }
    #pragma unroll
    for (int r = 0; r < 16; ++r) atomicAdd(&zl[r*64 + j], acc[r]);
  }
  __syncthreads();
  if (tid < 16){
    const int r = tid;
    float mx = -1e30f;
    for (int j = 0; j < 64; ++j){ float v = zl[r*64 + j] + db[j]; zl[r*64 + j] = v; mx = fmaxf(mx, v); }
    float s = 0.f;
    for (int j = 0; j < 64; ++j){ float e = fexp2((zl[r*64 + j] - mx) * 1.442695041f); zl[r*64 + j] = e; s += e; }
    mi[r] = frcp_(s);
  }
  __syncthreads();
  for (int it = 0; it < 4; ++it){
    int idx = tid + 256*it;
    int r = idx >> 6, j = idx & 63;
    out[(size_t)(row0 + r)*64 + j] = zl[r*64 + j] * mi[r];
  }
}

// ---------- workspace layout (bytes) ----------
#define OFF_SPEECH 0u
#define OFF_ENC    67108864u
#define OFF_KR     100663296u
#define OFF_WA     102760448u
#define OFF_X1     102891520u
#define OFF_Y1     136445952u
#define OFF_PCTX   170000384u   // ctx_acc: 64*2*512*4 = 262144 B
#define OFF_LACC   170262528u   // l_acc:   64*2*4     = 512 B
#define OFF_H      171051008u   // 64 KB
#define OFF_CTR    171116544u   // flags: 64*8*4 = 2 KB (4 KB reserved)

#define DYN_LDS    67584    // 128 rows x 264 ushorts

extern "C" void kernel_launch(void* const* d_in, const int* in_sizes, int n_in,
                              void* d_out, int out_size, void* d_ws, size_t ws_size,
                              hipStream_t stream){
  const float* trans  = (const float*)d_in[0];
  const float* speech = (const float*)d_in[1];
  const float* emb_W  = (const float*)d_in[2];
  const float* emb_b  = (const float*)d_in[3];
  const float* Ua_W[2]  = {(const float*)d_in[4],  (const float*)d_in[13]};
  const float* Ua_b[2]  = {(const float*)d_in[5],  (const float*)d_in[14]};
  const float* Wa_W[2]  = {(const float*)d_in[6],  (const float*)d_in[15]};
  const float* Wa_bv[2] = {(const float*)d_in[7],  (const float*)d_in[16]};
  const float* va_W[2]  = {(const float*)d_in[8],  (const float*)d_in[17]};
  // d_in[9]/d_in[18] = va_b: constant logit shift, softmax-invariant, dropped exactly.
  const float* Kw[2]    = {(const float*)d_in[10], (const float*)d_in[19]};
  const float* Rw[2]    = {(const float*)d_in[11], (const float*)d_in[20]};
  const float* bw[2]    = {(const float*)d_in[12], (const float*)d_in[21]};
  const float* m1W = (const float*)d_in[22];
  const float* m1b = (const float*)d_in[23];
  const float* m2W = (const float*)d_in[24];
  const float* m2b = (const float*)d_in[25];
  const float* dW  = (const float*)d_in[26];
  const float* db  = (const float*)d_in[27];

  char* ws = (char*)d_ws;
  unsigned short* speech_bf = (unsigned short*)(ws + OFF_SPEECH);
  unsigned short* enc  = (unsigned short*)(ws + OFF_ENC);
  unsigned short* KRP  = (unsigned short*)(ws + OFF_KR);
  unsigned short* Wab  = (unsigned short*)(ws + OFF_WA);
  float* x1   = (float*)(ws + OFF_X1);
  float* y1   = (float*)(ws + OFF_Y1);
  float* ctxa = (float*)(ws + OFF_PCTX);
  float* lacc = (float*)(ws + OFF_LACC);
  float* hg   = (float*)(ws + OFF_H);
  unsigned int* flg = (unsigned int*)(ws + OFF_CTR);
  float* y2 = x1;   // x1 dead after scan1 consumes it

  hipFuncSetAttribute((const void*)scan_kernel,
                      hipFuncAttributeMaxDynamicSharedMemorySize, DYN_LDS);

  pack_bf16v<<<4096, 256, 0, stream>>>(speech, speech_bf, B*TE*EE/4);
  emb_gemm<<<2048, 256, 0, stream>>>(trans, emb_W, emb_b, x1);

  for (int L = 0; L < 2; ++L){
    enc_gemm<<<4096, 256, 0, stream>>>(speech, Ua_W[L], Ua_b[L], enc);
    pack_KRP<<<4096, 256, 0, stream>>>(Kw[L], Rw[L], KRP);
    pack_bf16v<<<64, 256, 0, stream>>>(Wa_W[L], Wab, UU*UU/4);
    hipMemsetAsync(flg, 0, 4096, stream);
    hipMemsetAsync(ctxa, 0, 262656, stream);   // ctx_acc + l_acc (contiguous)
    scan_kernel<<<512, 512, DYN_LDS, stream>>>(L == 0 ? x1 : y1, L == 0 ? y1 : y2,
        enc, speech_bf, KRP, Wab, Wa_bv[L], va_W[L], bw[L], ctxa, lacc, hg, flg);
  }

  head_kernel<<<2048, 256, 0, stream>>>(y2, m1W, m1b, m2W, m2b, dW, db, (float*)d_out);
  (void)in_sizes; (void)n_in; (void)out_size; (void)ws_size;
}